// Round 10
// baseline (702.314 us; speedup 1.0000x reference)
//
#include <hip/hip_runtime.h>

#define N_NODES 50000
#define N_EDGES 800000
#define SLOPE 0.15f

typedef unsigned short u16;
typedef __attribute__((ext_vector_type(8))) __bf16 bf16x8;
typedef __attribute__((ext_vector_type(4))) float f32x4;

static __device__ __forceinline__ float leaky(float v) { return v > 0.f ? v : SLOPE * v; }

// split fp32 into hi/lo bf16 pair: v ~= hi + lo, residual ~2^-17 relative
static __device__ __forceinline__ ushort2 split_bf(float v) {
    __bf16 h = (__bf16)v;
    float hf = (float)h;
    __bf16 l = (__bf16)(v - hf);
    ushort2 r;
    r.x = __builtin_bit_cast(unsigned short, h);
    r.y = __builtin_bit_cast(unsigned short, l);
    return r;
}

// async global->LDS 16B: HW writes lane's data to (wave-uniform lds base) + lane*16
static __device__ __forceinline__ void async_load16(const u16* g, u16* l) {
    __builtin_amdgcn_global_load_lds(
        (const __attribute__((address_space(1))) unsigned int*)g,
        (__attribute__((address_space(3))) unsigned int*)l, 16, 0, 0);
}

// ---------------- CSR build ----------------
__global__ void k_count(const int* __restrict__ dst, int* __restrict__ cnt) {
    int e = blockIdx.x * 256 + threadIdx.x;
    if (e < N_EDGES) atomicAdd(&cnt[dst[e]], 1);
}

// multi-block scan, stage 1: per-1024-block local exclusive scan + block total
__global__ __launch_bounds__(1024) void k_scan1(const int* __restrict__ cnt,
                                                int* __restrict__ offs,
                                                int* __restrict__ bsum) {
    __shared__ int wsum[16];
    int tid = threadIdx.x, lane = tid & 63, wv = tid >> 6;
    int i = blockIdx.x * 1024 + tid;
    int orig = (i < N_NODES) ? cnt[i] : 0;
    int v = orig;
#pragma unroll
    for (int d = 1; d < 64; d <<= 1) {
        int t = __shfl_up(v, d, 64);
        if (lane >= d) v += t;
    }
    if (lane == 63) wsum[wv] = v;
    __syncthreads();
    if (wv == 0) {
        int s = (lane < 16) ? wsum[lane] : 0;
#pragma unroll
        for (int d = 1; d < 16; d <<= 1) {
            int t = __shfl_up(s, d, 64);
            if (lane >= d) s += t;
        }
        if (lane < 16) wsum[lane] = s;
        if (lane == 15) bsum[blockIdx.x] = s;
    }
    __syncthreads();
    int wpre = (wv == 0) ? 0 : wsum[wv - 1];
    if (i < N_NODES) offs[i] = v + wpre - orig;
}

// stage 2: one wave scans the (<=64) block sums -> exclusive
__global__ void k_scan2(int* __restrict__ bsum, int nb) {
    int lane = threadIdx.x;
    int v = (lane < nb) ? bsum[lane] : 0;
    int s = v;
#pragma unroll
    for (int d = 1; d < 64; d <<= 1) {
        int t = __shfl_up(s, d, 64);
        if (lane >= d) s += t;
    }
    if (lane < nb) bsum[lane] = s - v;
}

// stage 3: add block offsets; emit cursor + inv
__global__ void k_scan3(const int* __restrict__ cnt, int* __restrict__ offs,
                        int* __restrict__ cursor, float* __restrict__ inv,
                        const int* __restrict__ bsum) {
    int i = blockIdx.x * 256 + threadIdx.x;
    if (i >= N_NODES) return;
    int c = cnt[i];
    int o = offs[i] + bsum[i >> 10];
    offs[i] = o;
    cursor[i] = o;
    inv[i] = 1.0f / (float)(c > 1 ? c : 1);
    if (i == 0) offs[N_NODES] = N_EDGES;
}

__global__ void k_fill(const int* __restrict__ src, const int* __restrict__ dst,
                       int* __restrict__ cursor, int* __restrict__ ssrc) {
    int e = blockIdx.x * 256 + threadIdx.x;
    if (e < N_EDGES) {
        int pos = atomicAdd(&cursor[dst[e]], 1);
        ssrc[pos] = src[e];
    }
}

// ---------------- mean aggregation (column-split) ----------------
template <int D, int STRIDE, int U, bool SPLIT>
__global__ __launch_bounds__(256) void k_agg(const float* __restrict__ tbl,
                                             const int* __restrict__ offs,
                                             const int* __restrict__ ssrc,
                                             const float* __restrict__ inv,
                                             float* __restrict__ outf,
                                             u16* __restrict__ oh, u16* __restrict__ ol) {
    constexpr int G = 256 / D;
    constexpr int LPG = 64 / G;
    int wid = (blockIdx.x * 256 + threadIdx.x) >> 6;
    if (wid >= N_NODES) return;
    const int coff = blockIdx.y * D;
    int lane = threadIdx.x & 63;
    int eg = lane / LPG;
    int cl = lane % LPG;
    int beg = offs[wid], end = offs[wid + 1];
    float4 acc[U];
#pragma unroll
    for (int j = 0; j < U; ++j) acc[j] = make_float4(0.f, 0.f, 0.f, 0.f);
    for (int e = beg + eg; e < end; e += U * G) {
        int idx[U]; float msk[U];
#pragma unroll
        for (int j = 0; j < U; ++j) {
            int ee = e + j * G;
            bool ok = ee < end;
            idx[j] = ssrc[ok ? ee : e];
            msk[j] = ok ? 1.f : 0.f;
        }
#pragma unroll
        for (int j = 0; j < U; ++j) {
            const float4 t = *(const float4*)(tbl + (size_t)idx[j] * STRIDE + coff + cl * 4);
            acc[j].x = fmaf(t.x, msk[j], acc[j].x);
            acc[j].y = fmaf(t.y, msk[j], acc[j].y);
            acc[j].z = fmaf(t.z, msk[j], acc[j].z);
            acc[j].w = fmaf(t.w, msk[j], acc[j].w);
        }
    }
#pragma unroll
    for (int j = 1; j < U; ++j) {
        acc[0].x += acc[j].x; acc[0].y += acc[j].y;
        acc[0].z += acc[j].z; acc[0].w += acc[j].w;
    }
    float a0 = acc[0].x, a1 = acc[0].y, a2 = acc[0].z, a3 = acc[0].w;
#pragma unroll
    for (int m = LPG; m < 64; m <<= 1) {
        a0 += __shfl_xor(a0, m, 64);
        a1 += __shfl_xor(a1, m, 64);
        a2 += __shfl_xor(a2, m, 64);
        a3 += __shfl_xor(a3, m, 64);
    }
    float wv = inv[wid];
    a0 *= wv; a1 *= wv; a2 *= wv; a3 *= wv;
    if (!SPLIT) {
        if (eg == 0)
            *(float4*)(outf + (size_t)wid * STRIDE + coff + cl * 4) = make_float4(a0, a1, a2, a3);
    } else {
        ushort2 s0 = split_bf(a0), s1 = split_bf(a1), s2 = split_bf(a2), s3 = split_bf(a3);
        if (eg == 0) {
            *(ushort4*)(oh + (size_t)wid * STRIDE + coff + cl * 4) = make_ushort4(s0.x, s1.x, s2.x, s3.x);
        } else if (eg == 1) {
            *(ushort4*)(ol + (size_t)wid * STRIDE + coff + cl * 4) = make_ushort4(s0.y, s1.y, s2.y, s3.y);
        }
    }
}

// ---------------- operand prep ----------------
__global__ void k_xsplit(const float* __restrict__ in, u16* __restrict__ oh,
                         u16* __restrict__ ol, int n4) {
    int i = blockIdx.x * 256 + threadIdx.x;
    if (i >= n4) return;
    float4 v = ((const float4*)in)[i];
    ushort2 s0 = split_bf(v.x), s1 = split_bf(v.y), s2 = split_bf(v.z), s3 = split_bf(v.w);
    ((ushort4*)oh)[i] = make_ushort4(s0.x, s1.x, s2.x, s3.x);
    ((ushort4*)ol)[i] = make_ushort4(s0.y, s1.y, s2.y, s3.y);
}

__global__ void k_wsplit(const float* __restrict__ W0, const float* __restrict__ W1,
                         const float* __restrict__ W2, const float* __restrict__ W3,
                         const float* __restrict__ W4, const float* __restrict__ W5,
                         u16* o0h, u16* o0l, u16* o1h, u16* o1l, u16* o2h, u16* o2l,
                         u16* o3h, u16* o3l, u16* o4h, u16* o4l, u16* o5h, u16* o5l) {
    const float* W; u16 *oh, *ol; int K, N;
    switch (blockIdx.y) {
        case 0: W = W0; oh = o0h; ol = o0l; K = 128; N = 512; break;
        case 1: W = W1; oh = o1h; ol = o1l; K = 128; N = 512; break;
        case 2: W = W2; oh = o2h; ol = o2l; K = 512; N = 256; break;
        case 3: W = W3; oh = o3h; ol = o3l; K = 512; N = 256; break;
        case 4: W = W4; oh = o4h; ol = o4l; K = 256; N = 64; break;
        default: W = W5; oh = o5h; ol = o5l; K = 256; N = 64; break;
    }
    int i = blockIdx.x * 256 + threadIdx.x;
    if (i >= K * N) return;
    int k = i / N, n = i - k * N;
    ushort2 s = split_bf(W[i]);
    size_t o = (size_t)n * K + k;
    oh[o] = s.x;
    ol[o] = s.y;
}

// ---------------- split-bf16 MFMA GEMM: 128x128 tile, single-buffer, 4 blocks/CU ------
__global__ __launch_bounds__(256, 4) void k_gemm_s(
    int M, int nct,
    const u16* __restrict__ A1h, const u16* __restrict__ A1l,
    const u16* __restrict__ B1h, const u16* __restrict__ B1l, int K1,
    const u16* __restrict__ A2h, const u16* __restrict__ A2l,
    const u16* __restrict__ B2h, const u16* __restrict__ B2l, int K2,
    const float* __restrict__ bias, int act, int colsplit,
    float* __restrict__ out1f, u16* __restrict__ out1h, u16* __restrict__ out1l, int n1,
    float* __restrict__ out2f, int n2) {
    __shared__ u16 Ash[4096], Asl[4096], Bsh[4096], Bsl[4096];
    const int tid = threadIdx.x;
    const int lane = tid & 63;
    const int w = tid >> 6;
    const int wm = w & 1, wn = w >> 1;
    const int fr = lane & 15;
    const int q = lane >> 4;

    const int mT = (M + 127) >> 7;
    const int lin = blockIdx.x;
    const int grp = lin / (8 * nct);
    const int idx = lin - grp * (8 * nct);
    const int ct = idx >> 3;
    const int s8 = idx & 7;
    const int rowt = grp * 8 + s8;
    if (rowt >= mT) return;
    const int brow = rowt * 128;
    const int bcol = ct * 128;

    const int T1 = K1 >> 5, T = T1 + (K2 >> 5);

    const int c0 = (w * 2 + 0) * 64 + lane;
    const int c1 = (w * 2 + 1) * 64 + lane;
    const int r0 = c0 >> 2, g0 = (c0 & 3) ^ ((r0 >> 1) & 3);
    const int r1 = c1 >> 2, g1 = (c1 & 3) ^ ((r1 >> 1) & 3);
    int ar0 = brow + r0; if (ar0 >= M) ar0 = M - 1;
    int ar1 = brow + r1; if (ar1 >= M) ar1 = M - 1;
    const int br0 = bcol + r0, br1 = bcol + r1;
    const int ub0 = (w * 2 + 0) * 512;
    const int ub1 = (w * 2 + 1) * 512;

    f32x4 acc[4][4] = {};

    for (int kt = 0; kt < T; ++kt) {
        const u16 *Ah, *Al, *Bh, *Bl; int K, k0;
        if (kt < T1) { Ah = A1h; Al = A1l; Bh = B1h; Bl = B1l; K = K1; k0 = kt * 32; }
        else         { Ah = A2h; Al = A2l; Bh = B2h; Bl = B2l; K = K2; k0 = (kt - T1) * 32; }
        __syncthreads();
        {
            size_t ga0 = (size_t)ar0 * K + k0 + g0 * 8;
            size_t ga1 = (size_t)ar1 * K + k0 + g1 * 8;
            size_t gb0 = (size_t)br0 * K + k0 + g0 * 8;
            size_t gb1 = (size_t)br1 * K + k0 + g1 * 8;
            async_load16(Ah + ga0, &Ash[ub0]);
            async_load16(Ah + ga1, &Ash[ub1]);
            async_load16(Al + ga0, &Asl[ub0]);
            async_load16(Al + ga1, &Asl[ub1]);
            async_load16(Bh + gb0, &Bsh[ub0]);
            async_load16(Bh + gb1, &Bsh[ub1]);
            async_load16(Bl + gb0, &Bsl[ub0]);
            async_load16(Bl + gb1, &Bsl[ub1]);
        }
        __syncthreads();
        bf16x8 fah[4], fal[4], fbh[4], fbl[4];
#pragma unroll
        for (int rt = 0; rt < 4; ++rt) {
            int row = wm * 64 + rt * 16 + fr;
            int ad = row * 32 + ((q ^ ((row >> 1) & 3)) * 8);
            fah[rt] = __builtin_bit_cast(bf16x8, *(const uint4*)&Ash[ad]);
            fal[rt] = __builtin_bit_cast(bf16x8, *(const uint4*)&Asl[ad]);
        }
#pragma unroll
        for (int ctf = 0; ctf < 4; ++ctf) {
            int row = wn * 64 + ctf * 16 + fr;
            int ad = row * 32 + ((q ^ ((row >> 1) & 3)) * 8);
            fbh[ctf] = __builtin_bit_cast(bf16x8, *(const uint4*)&Bsh[ad]);
            fbl[ctf] = __builtin_bit_cast(bf16x8, *(const uint4*)&Bsl[ad]);
        }
#pragma unroll
        for (int rt = 0; rt < 4; ++rt)
#pragma unroll
            for (int ctf = 0; ctf < 4; ++ctf) {
                acc[rt][ctf] = __builtin_amdgcn_mfma_f32_16x16x32_bf16(fah[rt], fbh[ctf], acc[rt][ctf], 0, 0, 0);
                acc[rt][ctf] = __builtin_amdgcn_mfma_f32_16x16x32_bf16(fah[rt], fbl[ctf], acc[rt][ctf], 0, 0, 0);
                acc[rt][ctf] = __builtin_amdgcn_mfma_f32_16x16x32_bf16(fal[rt], fbh[ctf], acc[rt][ctf], 0, 0, 0);
            }
    }

#pragma unroll
    for (int rt = 0; rt < 4; ++rt) {
        int rowb = brow + wm * 64 + rt * 16 + q * 4;
#pragma unroll
        for (int ctf = 0; ctf < 4; ++ctf) {
            int col = bcol + wn * 64 + ctf * 16 + fr;
            float b = bias ? bias[col] : 0.f;
#pragma unroll
            for (int r = 0; r < 4; ++r) {
                int row = rowb + r;
                if (row >= M) continue;
                float v = acc[rt][ctf][r] + b;
                if (act) v = leaky(v);
                if (col < colsplit) {
                    if (out1f) out1f[(size_t)row * n1 + col] = v;
                    if (out1h) {
                        ushort2 s = split_bf(v);
                        out1h[(size_t)row * n1 + col] = s.x;
                        out1l[(size_t)row * n1 + col] = s.y;
                    }
                } else {
                    out2f[(size_t)row * n2 + (col - colsplit)] = v;
                }
            }
        }
    }
}

// -------- fused dispatch: y2-GEMM (blocks < gemmBlocks) || agg2 (remaining blocks) -----
// a2f MUST be disjoint from h1 planes (GEMM A operand) — race otherwise.
__global__ __launch_bounds__(256, 4) void k_y2agg(
    int M,
    const u16* __restrict__ Ah_, const u16* __restrict__ Al_,
    const u16* __restrict__ Bh_, const u16* __restrict__ Bl_,
    float* __restrict__ y2f,
    const float* __restrict__ tbl, const int* __restrict__ offs,
    const int* __restrict__ ssrc, const float* __restrict__ inv,
    float* __restrict__ a2f, int gemmBlocks) {
    __shared__ u16 Ash[4096], Asl[4096], Bsh[4096], Bsl[4096];
    const int tid = threadIdx.x;
    const int lane = tid & 63;

    if (blockIdx.x >= gemmBlocks) {
        // ---- aggregation path: D=64, STRIDE=256, U=8 ----
        constexpr int U = 8;
        const int abid = blockIdx.x - gemmBlocks;
        const int chunk = abid & 3;
        const int nodeblk = abid >> 2;
        int wid = nodeblk * 4 + (tid >> 6);
        if (wid >= N_NODES) return;
        const int coff = chunk * 64;
        int eg = lane >> 4;
        int cl = lane & 15;
        int beg = offs[wid], end = offs[wid + 1];
        float4 acc[U];
#pragma unroll
        for (int j = 0; j < U; ++j) acc[j] = make_float4(0.f, 0.f, 0.f, 0.f);
        for (int e = beg + eg; e < end; e += U * 4) {
            int idx[U]; float msk[U];
#pragma unroll
            for (int j = 0; j < U; ++j) {
                int ee = e + j * 4;
                bool ok = ee < end;
                idx[j] = ssrc[ok ? ee : e];
                msk[j] = ok ? 1.f : 0.f;
            }
#pragma unroll
            for (int j = 0; j < U; ++j) {
                const float4 t = *(const float4*)(tbl + (size_t)idx[j] * 256 + coff + cl * 4);
                acc[j].x = fmaf(t.x, msk[j], acc[j].x);
                acc[j].y = fmaf(t.y, msk[j], acc[j].y);
                acc[j].z = fmaf(t.z, msk[j], acc[j].z);
                acc[j].w = fmaf(t.w, msk[j], acc[j].w);
            }
        }
#pragma unroll
        for (int j = 1; j < U; ++j) {
            acc[0].x += acc[j].x; acc[0].y += acc[j].y;
            acc[0].z += acc[j].z; acc[0].w += acc[j].w;
        }
        float a0 = acc[0].x, a1 = acc[0].y, a2 = acc[0].z, a3 = acc[0].w;
#pragma unroll
        for (int m = 16; m < 64; m <<= 1) {
            a0 += __shfl_xor(a0, m, 64);
            a1 += __shfl_xor(a1, m, 64);
            a2 += __shfl_xor(a2, m, 64);
            a3 += __shfl_xor(a3, m, 64);
        }
        float wv = inv[wid];
        if (eg == 0)
            *(float4*)(a2f + (size_t)wid * 256 + coff + cl * 4) =
                make_float4(a0 * wv, a1 * wv, a2 * wv, a3 * wv);
        return;
    }

    // ---- GEMM path: y2 = h1@W2r, K=512, nct=2 ----
    const int w = tid >> 6;
    const int wm = w & 1, wn = w >> 1;
    const int fr = lane & 15;
    const int q = lane >> 4;
    const int K = 512;
    const int mT = (M + 127) >> 7;
    const int lin = blockIdx.x;
    const int grp = lin >> 4;
    const int idx = lin & 15;
    const int ct = idx >> 3;
    const int rowt = grp * 8 + (idx & 7);
    if (rowt >= mT) return;
    const int brow = rowt * 128;
    const int bcol = ct * 128;

    const int c0 = (w * 2 + 0) * 64 + lane;
    const int c1 = (w * 2 + 1) * 64 + lane;
    const int r0 = c0 >> 2, g0 = (c0 & 3) ^ ((r0 >> 1) & 3);
    const int r1 = c1 >> 2, g1 = (c1 & 3) ^ ((r1 >> 1) & 3);
    int ar0 = brow + r0; if (ar0 >= M) ar0 = M - 1;
    int ar1 = brow + r1; if (ar1 >= M) ar1 = M - 1;
    const int br0 = bcol + r0, br1 = bcol + r1;
    const int ub0 = (w * 2 + 0) * 512;
    const int ub1 = (w * 2 + 1) * 512;

    f32x4 acc[4][4] = {};

    for (int kt = 0; kt < (K >> 5); ++kt) {
        int k0 = kt * 32;
        __syncthreads();
        {
            size_t ga0 = (size_t)ar0 * K + k0 + g0 * 8;
            size_t ga1 = (size_t)ar1 * K + k0 + g1 * 8;
            size_t gb0 = (size_t)br0 * K + k0 + g0 * 8;
            size_t gb1 = (size_t)br1 * K + k0 + g1 * 8;
            async_load16(Ah_ + ga0, &Ash[ub0]);
            async_load16(Ah_ + ga1, &Ash[ub1]);
            async_load16(Al_ + ga0, &Asl[ub0]);
            async_load16(Al_ + ga1, &Asl[ub1]);
            async_load16(Bh_ + gb0, &Bsh[ub0]);
            async_load16(Bh_ + gb1, &Bsh[ub1]);
            async_load16(Bl_ + gb0, &Bsl[ub0]);
            async_load16(Bl_ + gb1, &Bsl[ub1]);
        }
        __syncthreads();
        bf16x8 fah[4], fal[4], fbh[4], fbl[4];
#pragma unroll
        for (int rt = 0; rt < 4; ++rt) {
            int row = wm * 64 + rt * 16 + fr;
            int ad = row * 32 + ((q ^ ((row >> 1) & 3)) * 8);
            fah[rt] = __builtin_bit_cast(bf16x8, *(const uint4*)&Ash[ad]);
            fal[rt] = __builtin_bit_cast(bf16x8, *(const uint4*)&Asl[ad]);
        }
#pragma unroll
        for (int ctf = 0; ctf < 4; ++ctf) {
            int row = wn * 64 + ctf * 16 + fr;
            int ad = row * 32 + ((q ^ ((row >> 1) & 3)) * 8);
            fbh[ctf] = __builtin_bit_cast(bf16x8, *(const uint4*)&Bsh[ad]);
            fbl[ctf] = __builtin_bit_cast(bf16x8, *(const uint4*)&Bsl[ad]);
        }
#pragma unroll
        for (int rt = 0; rt < 4; ++rt)
#pragma unroll
            for (int ctf = 0; ctf < 4; ++ctf) {
                acc[rt][ctf] = __builtin_amdgcn_mfma_f32_16x16x32_bf16(fah[rt], fbh[ctf], acc[rt][ctf], 0, 0, 0);
                acc[rt][ctf] = __builtin_amdgcn_mfma_f32_16x16x32_bf16(fah[rt], fbl[ctf], acc[rt][ctf], 0, 0, 0);
                acc[rt][ctf] = __builtin_amdgcn_mfma_f32_16x16x32_bf16(fal[rt], fbh[ctf], acc[rt][ctf], 0, 0, 0);
            }
    }

#pragma unroll
    for (int rt = 0; rt < 4; ++rt) {
        int rowb = brow + wm * 64 + rt * 16 + q * 4;
#pragma unroll
        for (int ctf = 0; ctf < 4; ++ctf) {
            int col = bcol + wn * 64 + ctf * 16 + fr;
#pragma unroll
            for (int r = 0; r < 4; ++r) {
                int row = rowb + r;
                if (row >= M) continue;
                y2f[(size_t)row * 256 + col] = acc[rt][ctf][r];
            }
        }
    }
}

// ---------------- h2 epilogue: h2 = leaky(y2 + a2 + b2) -> split planes ----------------
__global__ __launch_bounds__(256) void k_post2(const float* __restrict__ y2,
                                               const float* __restrict__ a2,
                                               const float* __restrict__ b2,
                                               u16* __restrict__ oh, u16* __restrict__ ol) {
    int i = blockIdx.x * 256 + threadIdx.x;
    if (i >= N_NODES * 64) return;
    float4 y = ((const float4*)y2)[i];
    float4 a = ((const float4*)a2)[i];
    const float4 b = *(const float4*)(b2 + (i & 63) * 4);
    float v0 = leaky(y.x + a.x + b.x);
    float v1 = leaky(y.y + a.y + b.y);
    float v2 = leaky(y.z + a.z + b.z);
    float v3 = leaky(y.w + a.w + b.w);
    ushort2 s0 = split_bf(v0), s1 = split_bf(v1), s2 = split_bf(v2), s3 = split_bf(v3);
    ((ushort4*)oh)[i] = make_ushort4(s0.x, s1.x, s2.x, s3.x);
    ((ushort4*)ol)[i] = make_ushort4(s0.y, s1.y, s2.y, s3.y);
}

// ---------------- fused head ----------------
__global__ __launch_bounds__(256) void k_head(const float* __restrict__ y3,
                                              const float* __restrict__ a3,
                                              const float* __restrict__ b3,
                                              const float* __restrict__ Wp, const float* __restrict__ bp,
                                              const float* __restrict__ Wf1, const float* __restrict__ bf1,
                                              const float* __restrict__ Wf2, const float* __restrict__ bf2,
                                              float* __restrict__ out) {
    __shared__ float sWp[64 * 32], sW1[32 * 32], sW2[32 * 2];
    __shared__ float sbp[32], sb1[32], sb2[2], sb3[64];
    int tid = threadIdx.x;
    for (int i = tid; i < 64 * 32; i += 256) sWp[i] = Wp[i];
    for (int i = tid; i < 32 * 32; i += 256) sW1[i] = Wf1[i];
    for (int i = tid; i < 64; i += 256) { sW2[i] = Wf2[i]; sb3[i] = b3[i]; }
    if (tid < 32) { sbp[tid] = bp[tid]; sb1[tid] = bf1[tid]; }
    if (tid < 2) sb2[tid] = bf2[tid];
    __syncthreads();
    int row = blockIdx.x * 256 + tid;
    if (row >= N_NODES) return;
    const float4* y4 = (const float4*)(y3 + (size_t)row * 64);
    const float4* a4 = (const float4*)(a3 + (size_t)row * 64);
    float xr[64];
#pragma unroll
    for (int i = 0; i < 16; ++i) {
        float4 yv = y4[i], av = a4[i];
        xr[i * 4 + 0] = leaky(yv.x + av.x + sb3[i * 4 + 0]);
        xr[i * 4 + 1] = leaky(yv.y + av.y + sb3[i * 4 + 1]);
        xr[i * 4 + 2] = leaky(yv.z + av.z + sb3[i * 4 + 2]);
        xr[i * 4 + 3] = leaky(yv.w + av.w + sb3[i * 4 + 3]);
    }
    float h4[32];
    for (int o = 0; o < 32; ++o) {
        float s = sbp[o];
#pragma unroll
        for (int i = 0; i < 64; ++i) s += xr[i] * sWp[i * 32 + o];
        h4[o] = s;
    }
    float h5[32];
    for (int o = 0; o < 32; ++o) {
        float s = sb1[o];
#pragma unroll
        for (int i = 0; i < 32; ++i) s += h4[i] * sW1[i * 32 + o];
        h5[o] = leaky(s);
    }
#pragma unroll
    for (int o = 0; o < 2; ++o) {
        float s = sb2[o];
#pragma unroll
        for (int i = 0; i < 32; ++i) s += h5[i] * sW2[i * 2 + o];
        out[(size_t)row * 2 + o] = s;
    }
}

// ---------------- launch ----------------
extern "C" void kernel_launch(void* const* d_in, const int* in_sizes, int n_in,
                              void* d_out, int out_size, void* d_ws, size_t ws_size,
                              hipStream_t stream) {
    const float* x   = (const float*)d_in[0];
    const int*   ei  = (const int*)d_in[1];
    const float* W1l = (const float*)d_in[5];
    const float* b1  = (const float*)d_in[6];
    const float* W1r = (const float*)d_in[7];
    const float* W2l = (const float*)d_in[8];
    const float* b2  = (const float*)d_in[9];
    const float* W2r = (const float*)d_in[10];
    const float* W3l = (const float*)d_in[11];
    const float* b3  = (const float*)d_in[12];
    const float* W3r = (const float*)d_in[13];
    const float* Wp  = (const float*)d_in[14];
    const float* bp  = (const float*)d_in[15];
    const float* Wf1 = (const float*)d_in[16];
    const float* bf1 = (const float*)d_in[17];
    const float* Wf2 = (const float*)d_in[18];
    const float* bf2 = (const float*)d_in[19];
    float* out = (float*)d_out;
    (void)in_sizes; (void)n_in; (void)out_size;

    const int* src = ei;
    const int* dst = ei + N_EDGES;

    char* base = (char*)d_ws;
    size_t off = 0;
    auto alloc = [&](size_t bytes) -> void* {
        void* r = base + off;
        off = (off + bytes + 255) & ~(size_t)255;
        return r;
    };
    const size_t NN = N_NODES;
    int*   cnt    = (int*)alloc(NN * 4);
    int*   offs   = (int*)alloc((NN + 1) * 4);
    int*   cursor = (int*)alloc(NN * 4);
    float* inv    = (float*)alloc(NN * 4);
    int*   bsum   = (int*)alloc(64 * 4);
    int*   ssrc   = (int*)alloc((size_t)N_EDGES * 4);
    u16* w1lh = (u16*)alloc(128 * 512 * 2); u16* w1ll = (u16*)alloc(128 * 512 * 2);
    u16* w1rh = (u16*)alloc(128 * 512 * 2); u16* w1rl = (u16*)alloc(128 * 512 * 2);
    u16* w2ch = (u16*)alloc(512 * 512 * 2); u16* w2cl = (u16*)alloc(512 * 512 * 2);
    u16* w3ch = (u16*)alloc(128 * 256 * 2); u16* w3cl = (u16*)alloc(128 * 256 * 2);

    // Live-range-aliased regions (~205 MB)
    char* regA = (char*)alloc(NN * 256 * 4);       // xh|xl|axh|axl -> z2 -> h2h|h2l
    char* regB = (char*)alloc(NN * 512 * 2 * 2);   // h1h|h1l -> a2 (fallback path only)
    char* regD = (char*)alloc(NN * 256 * 4);       // y2 -> z3|y3|a3

    u16* xh  = (u16*)regA;
    u16* xl  = xh + NN * 128;
    u16* axh = xl + NN * 128;
    u16* axl = axh + NN * 128;
    u16* h1h = (u16*)regB;
    u16* h1l = h1h + NN * 512;
    float* z2 = (float*)regA;
    float* a2B = (float*)regB;                     // fallback a2 (aliases h1 — only safe AFTER both L2 GEMMs)
    u16* h2h = (u16*)regA;
    u16* h2l = h2h + NN * 256;
    float* y2f = (float*)regD;
    float* z3f = (float*)regD;
    float* y3f = z3f + NN * 64;
    float* a3f = y3f + NN * 64;

    // Optional extra region for the fused (y2-GEMM || agg2) path: a2 must be disjoint
    // from h1 (GEMM reads it concurrently). Engage only if the workspace fits.
    size_t a2_off = off;
    const size_t a2_bytes = NN * 256 * 4;
    const bool fused_l2 = (a2_off + a2_bytes) <= ws_size;
    float* a2F = (float*)(base + a2_off);

    // CSR build
    hipMemsetAsync(cnt, 0, NN * 4, stream);
    k_count<<<(N_EDGES + 255) / 256, 256, 0, stream>>>(dst, cnt);
    const int nb = (N_NODES + 1023) / 1024;   // 49
    k_scan1<<<nb, 1024, 0, stream>>>(cnt, offs, bsum);
    k_scan2<<<1, 64, 0, stream>>>(bsum, nb);
    k_scan3<<<(N_NODES + 255) / 256, 256, 0, stream>>>(cnt, offs, cursor, inv, bsum);
    k_fill<<<(N_EDGES + 255) / 256, 256, 0, stream>>>(src, dst, cursor, ssrc);

    // operand prep
    k_xsplit<<<(N_NODES * 128 / 4 + 255) / 256, 256, 0, stream>>>(x, xh, xl, N_NODES * 128 / 4);
    k_wsplit<<<dim3(512, 6), 256, 0, stream>>>(W1l, W1r, W2l, W2r, W3l, W3r,
        w1lh, w1ll, w1rh, w1rl,
        w2ch, w2cl, w2ch + 256 * 512, w2cl + 256 * 512,
        w3ch, w3cl, w3ch + 64 * 256, w3cl + 64 * 256);

    const int aggGrid = (N_NODES + 3) / 4;             // 12500
    const int mT = (N_NODES + 127) / 128;              // 391
    const int grid4 = ((mT + 7) / 8) * 32;             // nct=4
    const int grid2 = ((mT + 7) / 8) * 16;             // nct=2
    const int grid1 = ((mT + 7) / 8) * 8;              // nct=1

    // layer 1: aggX = S x (split, 2 chunks); h1 = leaky(aggX@W1l + x@W1r + b1)
    k_agg<64, 128, 8, true><<<dim3(aggGrid, 2), 256, 0, stream>>>(
        x, offs, ssrc, inv, nullptr, axh, axl);
    k_gemm_s<<<grid4, 256, 0, stream>>>(N_NODES, 4,
        axh, axl, w1lh, w1ll, 128, xh, xl, w1rh, w1rl, 128,
        b1, 1, 512, nullptr, h1h, h1l, 512, nullptr, 0);

    // layer 2
    if (fused_l2) {
        // z2 = h1@W2l; then FUSED (y2 = h1@W2r || a2F = S z2); h2 = leaky(y2+a2F+b2)
        k_gemm_s<<<grid2, 256, 0, stream>>>(N_NODES, 2,
            h1h, h1l, w2ch, w2cl, 512, nullptr, nullptr, nullptr, nullptr, 0,
            nullptr, 0, 256, z2, nullptr, nullptr, 256, nullptr, 0);
        k_y2agg<<<grid2 + aggGrid * 4, 256, 0, stream>>>(N_NODES,
            h1h, h1l, w2ch + 256 * 512, w2cl + 256 * 512, y2f,
            z2, offs, ssrc, inv, a2F, grid2);
        k_post2<<<(N_NODES * 64 + 255) / 256, 256, 0, stream>>>(y2f, a2F, b2, h2h, h2l);
    } else {
        // round-8 ordering: [z2|y2] in one GEMM; agg writes a2 over dead h1
        k_gemm_s<<<grid4, 256, 0, stream>>>(N_NODES, 4,
            h1h, h1l, w2ch, w2cl, 512, nullptr, nullptr, nullptr, nullptr, 0,
            nullptr, 0, 256, z2, nullptr, nullptr, 256, y2f, 256);
        k_agg<128, 256, 8, false><<<dim3(aggGrid, 2), 256, 0, stream>>>(
            z2, offs, ssrc, inv, a2B, nullptr, nullptr);
        k_post2<<<(N_NODES * 64 + 255) / 256, 256, 0, stream>>>(y2f, a2B, b2, h2h, h2l);
    }

    // layer 3 (fused cols): [z3 | y3] = h2 @ [W3l | W3r]; a3 = S z3
    k_gemm_s<<<grid1, 256, 0, stream>>>(N_NODES, 1,
        h2h, h2l, w3ch, w3cl, 256, nullptr, nullptr, nullptr, nullptr, 0,
        nullptr, 0, 64, z3f, nullptr, nullptr, 64, y3f, 64);
    k_agg<32, 64, 8, false><<<dim3(aggGrid, 2), 256, 0, stream>>>(
        z3f, offs, ssrc, inv, a3f, nullptr, nullptr);

    // head
    k_head<<<(N_NODES + 255) / 256, 256, 0, stream>>>(y3f, a3f, b3,
        Wp, bp, Wf1, bf1, Wf2, bf2, out);
}

// Round 11
// 650.110 us; speedup vs baseline: 1.0803x; 1.0803x over previous
//
#include <hip/hip_runtime.h>

#define N_NODES 50000
#define N_EDGES 800000
#define SLOPE 0.15f

typedef unsigned short u16;
typedef __attribute__((ext_vector_type(8))) __bf16 bf16x8;
typedef __attribute__((ext_vector_type(4))) float f32x4;

static __device__ __forceinline__ float leaky(float v) { return v > 0.f ? v : SLOPE * v; }

// split fp32 into hi/lo bf16 pair: v ~= hi + lo, residual ~2^-17 relative
static __device__ __forceinline__ ushort2 split_bf(float v) {
    __bf16 h = (__bf16)v;
    float hf = (float)h;
    __bf16 l = (__bf16)(v - hf);
    ushort2 r;
    r.x = __builtin_bit_cast(unsigned short, h);
    r.y = __builtin_bit_cast(unsigned short, l);
    return r;
}

// async global->LDS 16B: HW writes lane's data to (wave-uniform lds base) + lane*16
static __device__ __forceinline__ void async_load16(const u16* g, u16* l) {
    __builtin_amdgcn_global_load_lds(
        (const __attribute__((address_space(1))) unsigned int*)g,
        (__attribute__((address_space(3))) unsigned int*)l, 16, 0, 0);
}

// ---------------- merged prep: edge count | x split | weight transpose+split ----------
// block ranges: [0,3125) count; [3125,9375) xsplit; [9375,11039) wsplit
__global__ void k_prep(const int* __restrict__ dst, int* __restrict__ cnt,
                       const float* __restrict__ x, u16* __restrict__ xh, u16* __restrict__ xl,
                       const float* __restrict__ W1l, const float* __restrict__ W1r,
                       const float* __restrict__ W2l, const float* __restrict__ W2r,
                       const float* __restrict__ W3l, const float* __restrict__ W3r,
                       u16* w1lh, u16* w1ll, u16* w1rh, u16* w1rl,
                       u16* w2ch, u16* w2cl, u16* w3ch, u16* w3cl) {
    int b = blockIdx.x, tid = threadIdx.x;
    if (b < 3125) {
        int e = b * 256 + tid;
        if (e < N_EDGES) atomicAdd(&cnt[dst[e]], 1);
        return;
    }
    b -= 3125;
    if (b < 6250) {
        int i = b * 256 + tid;              // over n4 = 1.6M float4s
        if (i >= N_NODES * 32) return;
        float4 v = ((const float4*)x)[i];
        ushort2 s0 = split_bf(v.x), s1 = split_bf(v.y), s2 = split_bf(v.z), s3 = split_bf(v.w);
        ((ushort4*)xh)[i] = make_ushort4(s0.x, s1.x, s2.x, s3.x);
        ((ushort4*)xl)[i] = make_ushort4(s0.y, s1.y, s2.y, s3.y);
        return;
    }
    b -= 6250;
    const float* W; u16 *oh, *ol; int K, N;
    if (b < 256)       { W = W1l; oh = w1lh; ol = w1ll; K = 128; N = 512; }
    else if (b < 512)  { W = W1r; oh = w1rh; ol = w1rl; K = 128; N = 512; b -= 256; }
    else if (b < 1024) { W = W2l; oh = w2ch; ol = w2cl; K = 512; N = 256; b -= 512; }
    else if (b < 1536) { W = W2r; oh = w2ch + 256 * 512; ol = w2cl + 256 * 512; K = 512; N = 256; b -= 1024; }
    else if (b < 1600) { W = W3l; oh = w3ch; ol = w3cl; K = 256; N = 64; b -= 1536; }
    else               { W = W3r; oh = w3ch + 64 * 256; ol = w3cl + 64 * 256; K = 256; N = 64; b -= 1600; }
    int i = b * 256 + tid;
    if (i >= K * N) return;
    int k = i / N, n = i - k * N;
    ushort2 s = split_bf(W[i]);
    size_t o = (size_t)n * K + k;   // W^T [N][K]
    oh[o] = s.x;
    ol[o] = s.y;
}

// multi-block scan, stage 1: per-1024-block local exclusive scan + block total
__global__ __launch_bounds__(1024) void k_scan1(const int* __restrict__ cnt,
                                                int* __restrict__ offs,
                                                int* __restrict__ bsum) {
    __shared__ int wsum[16];
    int tid = threadIdx.x, lane = tid & 63, wv = tid >> 6;
    int i = blockIdx.x * 1024 + tid;
    int orig = (i < N_NODES) ? cnt[i] : 0;
    int v = orig;
#pragma unroll
    for (int d = 1; d < 64; d <<= 1) {
        int t = __shfl_up(v, d, 64);
        if (lane >= d) v += t;
    }
    if (lane == 63) wsum[wv] = v;
    __syncthreads();
    if (wv == 0) {
        int s = (lane < 16) ? wsum[lane] : 0;
#pragma unroll
        for (int d = 1; d < 16; d <<= 1) {
            int t = __shfl_up(s, d, 64);
            if (lane >= d) s += t;
        }
        if (lane < 16) wsum[lane] = s;
        if (lane == 15) bsum[blockIdx.x] = s;
    }
    __syncthreads();
    int wpre = (wv == 0) ? 0 : wsum[wv - 1];
    if (i < N_NODES) offs[i] = v + wpre - orig;
}

// stage 2: one wave scans the (<=64) block sums -> exclusive
__global__ void k_scan2(int* __restrict__ bsum, int nb) {
    int lane = threadIdx.x;
    int v = (lane < nb) ? bsum[lane] : 0;
    int s = v;
#pragma unroll
    for (int d = 1; d < 64; d <<= 1) {
        int t = __shfl_up(s, d, 64);
        if (lane >= d) s += t;
    }
    if (lane < nb) bsum[lane] = s - v;
}

// stage 3: add block offsets; emit cursor + inv
__global__ void k_scan3(const int* __restrict__ cnt, int* __restrict__ offs,
                        int* __restrict__ cursor, float* __restrict__ inv,
                        const int* __restrict__ bsum) {
    int i = blockIdx.x * 256 + threadIdx.x;
    if (i >= N_NODES) return;
    int c = cnt[i];
    int o = offs[i] + bsum[i >> 10];
    offs[i] = o;
    cursor[i] = o;
    inv[i] = 1.0f / (float)(c > 1 ? c : 1);
    if (i == 0) offs[N_NODES] = N_EDGES;
}

__global__ void k_fill(const int* __restrict__ src, const int* __restrict__ dst,
                       int* __restrict__ cursor, int* __restrict__ ssrc) {
    int e = blockIdx.x * 256 + threadIdx.x;
    if (e < N_EDGES) {
        int pos = atomicAdd(&cursor[dst[e]], 1);
        ssrc[pos] = src[e];
    }
}

// ---------------- mean aggregation (column-split) with fused epilogues ----------------
// EPI: 0 = f32 out; 1 = split planes out; 2 = leaky(y+a+bias) -> split planes (h2);
//      3 = leaky(y+a+bias) -> f32 (h3).
template <int D, int STRIDE, int U, int EPI>
__global__ __launch_bounds__(256) void k_agg(const float* __restrict__ tbl,
                                             const int* __restrict__ offs,
                                             const int* __restrict__ ssrc,
                                             const float* __restrict__ inv,
                                             const float* __restrict__ y,
                                             const float* __restrict__ bias,
                                             float* __restrict__ outf,
                                             u16* __restrict__ oh, u16* __restrict__ ol) {
    constexpr int G = 256 / D;
    constexpr int LPG = 64 / G;
    int wid = (blockIdx.x * 256 + threadIdx.x) >> 6;
    if (wid >= N_NODES) return;
    const int coff = blockIdx.y * D;
    int lane = threadIdx.x & 63;
    int eg = lane / LPG;
    int cl = lane % LPG;
    int beg = offs[wid], end = offs[wid + 1];
    float4 acc[U];
#pragma unroll
    for (int j = 0; j < U; ++j) acc[j] = make_float4(0.f, 0.f, 0.f, 0.f);
    for (int e = beg + eg; e < end; e += U * G) {
        int idx[U]; float msk[U];
#pragma unroll
        for (int j = 0; j < U; ++j) {
            int ee = e + j * G;
            bool ok = ee < end;
            idx[j] = ssrc[ok ? ee : e];
            msk[j] = ok ? 1.f : 0.f;
        }
#pragma unroll
        for (int j = 0; j < U; ++j) {
            const float4 t = *(const float4*)(tbl + (size_t)idx[j] * STRIDE + coff + cl * 4);
            acc[j].x = fmaf(t.x, msk[j], acc[j].x);
            acc[j].y = fmaf(t.y, msk[j], acc[j].y);
            acc[j].z = fmaf(t.z, msk[j], acc[j].z);
            acc[j].w = fmaf(t.w, msk[j], acc[j].w);
        }
    }
#pragma unroll
    for (int j = 1; j < U; ++j) {
        acc[0].x += acc[j].x; acc[0].y += acc[j].y;
        acc[0].z += acc[j].z; acc[0].w += acc[j].w;
    }
    float a0 = acc[0].x, a1 = acc[0].y, a2 = acc[0].z, a3 = acc[0].w;
#pragma unroll
    for (int m = LPG; m < 64; m <<= 1) {
        a0 += __shfl_xor(a0, m, 64);
        a1 += __shfl_xor(a1, m, 64);
        a2 += __shfl_xor(a2, m, 64);
        a3 += __shfl_xor(a3, m, 64);
    }
    float wv = inv[wid];
    a0 *= wv; a1 *= wv; a2 *= wv; a3 *= wv;
    if (eg != 0) return;
    const size_t ob = (size_t)wid * STRIDE + coff + cl * 4;
    if (EPI == 0) {
        *(float4*)(outf + ob) = make_float4(a0, a1, a2, a3);
    } else if (EPI == 1) {
        ushort2 s0 = split_bf(a0), s1 = split_bf(a1), s2 = split_bf(a2), s3 = split_bf(a3);
        *(ushort4*)(oh + ob) = make_ushort4(s0.x, s1.x, s2.x, s3.x);
        *(ushort4*)(ol + ob) = make_ushort4(s0.y, s1.y, s2.y, s3.y);
    } else {
        float4 yv = *(const float4*)(y + ob);
        float4 bv = *(const float4*)(bias + coff + cl * 4);
        float v0 = leaky(a0 + yv.x + bv.x);
        float v1 = leaky(a1 + yv.y + bv.y);
        float v2 = leaky(a2 + yv.z + bv.z);
        float v3 = leaky(a3 + yv.w + bv.w);
        if (EPI == 2) {
            ushort2 s0 = split_bf(v0), s1 = split_bf(v1), s2 = split_bf(v2), s3 = split_bf(v3);
            *(ushort4*)(oh + ob) = make_ushort4(s0.x, s1.x, s2.x, s3.x);
            *(ushort4*)(ol + ob) = make_ushort4(s0.y, s1.y, s2.y, s3.y);
        } else {
            *(float4*)(outf + ob) = make_float4(v0, v1, v2, v3);
        }
    }
}

// ---------------- split-bf16 MFMA GEMM: 128x128 tile, single-buffer, 4 blocks/CU ------
__global__ __launch_bounds__(256, 4) void k_gemm_s(
    int M, int nct,
    const u16* __restrict__ A1h, const u16* __restrict__ A1l,
    const u16* __restrict__ B1h, const u16* __restrict__ B1l, int K1,
    const u16* __restrict__ A2h, const u16* __restrict__ A2l,
    const u16* __restrict__ B2h, const u16* __restrict__ B2l, int K2,
    const float* __restrict__ bias, int act, int colsplit,
    float* __restrict__ out1f, u16* __restrict__ out1h, u16* __restrict__ out1l, int n1,
    float* __restrict__ out2f, int n2) {
    __shared__ u16 Ash[4096], Asl[4096], Bsh[4096], Bsl[4096];
    const int tid = threadIdx.x;
    const int lane = tid & 63;
    const int w = tid >> 6;
    const int wm = w & 1, wn = w >> 1;
    const int fr = lane & 15;
    const int q = lane >> 4;

    const int mT = (M + 127) >> 7;
    const int lin = blockIdx.x;
    const int grp = lin / (8 * nct);
    const int idx = lin - grp * (8 * nct);
    const int ct = idx >> 3;
    const int s8 = idx & 7;
    const int rowt = grp * 8 + s8;
    if (rowt >= mT) return;
    const int brow = rowt * 128;
    const int bcol = ct * 128;

    const int T1 = K1 >> 5, T = T1 + (K2 >> 5);

    const int c0 = (w * 2 + 0) * 64 + lane;
    const int c1 = (w * 2 + 1) * 64 + lane;
    const int r0 = c0 >> 2, g0 = (c0 & 3) ^ ((r0 >> 1) & 3);
    const int r1 = c1 >> 2, g1 = (c1 & 3) ^ ((r1 >> 1) & 3);
    int ar0 = brow + r0; if (ar0 >= M) ar0 = M - 1;
    int ar1 = brow + r1; if (ar1 >= M) ar1 = M - 1;
    const int br0 = bcol + r0, br1 = bcol + r1;
    const int ub0 = (w * 2 + 0) * 512;
    const int ub1 = (w * 2 + 1) * 512;

    f32x4 acc[4][4] = {};

    for (int kt = 0; kt < T; ++kt) {
        const u16 *Ah, *Al, *Bh, *Bl; int K, k0;
        if (kt < T1) { Ah = A1h; Al = A1l; Bh = B1h; Bl = B1l; K = K1; k0 = kt * 32; }
        else         { Ah = A2h; Al = A2l; Bh = B2h; Bl = B2l; K = K2; k0 = (kt - T1) * 32; }
        __syncthreads();
        {
            size_t ga0 = (size_t)ar0 * K + k0 + g0 * 8;
            size_t ga1 = (size_t)ar1 * K + k0 + g1 * 8;
            size_t gb0 = (size_t)br0 * K + k0 + g0 * 8;
            size_t gb1 = (size_t)br1 * K + k0 + g1 * 8;
            async_load16(Ah + ga0, &Ash[ub0]);
            async_load16(Ah + ga1, &Ash[ub1]);
            async_load16(Al + ga0, &Asl[ub0]);
            async_load16(Al + ga1, &Asl[ub1]);
            async_load16(Bh + gb0, &Bsh[ub0]);
            async_load16(Bh + gb1, &Bsh[ub1]);
            async_load16(Bl + gb0, &Bsl[ub0]);
            async_load16(Bl + gb1, &Bsl[ub1]);
        }
        __syncthreads();
        bf16x8 fah[4], fal[4], fbh[4], fbl[4];
#pragma unroll
        for (int rt = 0; rt < 4; ++rt) {
            int row = wm * 64 + rt * 16 + fr;
            int ad = row * 32 + ((q ^ ((row >> 1) & 3)) * 8);
            fah[rt] = __builtin_bit_cast(bf16x8, *(const uint4*)&Ash[ad]);
            fal[rt] = __builtin_bit_cast(bf16x8, *(const uint4*)&Asl[ad]);
        }
#pragma unroll
        for (int ctf = 0; ctf < 4; ++ctf) {
            int row = wn * 64 + ctf * 16 + fr;
            int ad = row * 32 + ((q ^ ((row >> 1) & 3)) * 8);
            fbh[ctf] = __builtin_bit_cast(bf16x8, *(const uint4*)&Bsh[ad]);
            fbl[ctf] = __builtin_bit_cast(bf16x8, *(const uint4*)&Bsl[ad]);
        }
#pragma unroll
        for (int rt = 0; rt < 4; ++rt)
#pragma unroll
            for (int ctf = 0; ctf < 4; ++ctf) {
                acc[rt][ctf] = __builtin_amdgcn_mfma_f32_16x16x32_bf16(fah[rt], fbh[ctf], acc[rt][ctf], 0, 0, 0);
                acc[rt][ctf] = __builtin_amdgcn_mfma_f32_16x16x32_bf16(fah[rt], fbl[ctf], acc[rt][ctf], 0, 0, 0);
                acc[rt][ctf] = __builtin_amdgcn_mfma_f32_16x16x32_bf16(fal[rt], fbh[ctf], acc[rt][ctf], 0, 0, 0);
            }
    }

#pragma unroll
    for (int rt = 0; rt < 4; ++rt) {
        int rowb = brow + wm * 64 + rt * 16 + q * 4;
#pragma unroll
        for (int ctf = 0; ctf < 4; ++ctf) {
            int col = bcol + wn * 64 + ctf * 16 + fr;
            float b = bias ? bias[col] : 0.f;
#pragma unroll
            for (int r = 0; r < 4; ++r) {
                int row = rowb + r;
                if (row >= M) continue;
                float v = acc[rt][ctf][r] + b;
                if (act) v = leaky(v);
                if (col < colsplit) {
                    if (out1f) out1f[(size_t)row * n1 + col] = v;
                    if (out1h) {
                        ushort2 s = split_bf(v);
                        out1h[(size_t)row * n1 + col] = s.x;
                        out1l[(size_t)row * n1 + col] = s.y;
                    }
                } else {
                    out2f[(size_t)row * n2 + (col - colsplit)] = v;
                }
            }
        }
    }
}

// ---------------- fused head: h3 -> pre_fc -> leaky(fc1) -> fc2 ------
__global__ __launch_bounds__(256) void k_head(const float* __restrict__ h3,
                                              const float* __restrict__ Wp, const float* __restrict__ bp,
                                              const float* __restrict__ Wf1, const float* __restrict__ bf1,
                                              const float* __restrict__ Wf2, const float* __restrict__ bf2,
                                              float* __restrict__ out) {
    __shared__ float sWp[64 * 32], sW1[32 * 32], sW2[32 * 2];
    __shared__ float sbp[32], sb1[32], sb2[2];
    int tid = threadIdx.x;
    for (int i = tid; i < 64 * 32; i += 256) sWp[i] = Wp[i];
    for (int i = tid; i < 32 * 32; i += 256) sW1[i] = Wf1[i];
    for (int i = tid; i < 64; i += 256) sW2[i] = Wf2[i];
    if (tid < 32) { sbp[tid] = bp[tid]; sb1[tid] = bf1[tid]; }
    if (tid < 2) sb2[tid] = bf2[tid];
    __syncthreads();
    int row = blockIdx.x * 256 + tid;
    if (row >= N_NODES) return;
    const float4* h4v = (const float4*)(h3 + (size_t)row * 64);
    float xr[64];
#pragma unroll
    for (int i = 0; i < 16; ++i) {
        float4 v = h4v[i];
        xr[i * 4 + 0] = v.x; xr[i * 4 + 1] = v.y;
        xr[i * 4 + 2] = v.z; xr[i * 4 + 3] = v.w;
    }
    float h4[32];
    for (int o = 0; o < 32; ++o) {
        float s = sbp[o];
#pragma unroll
        for (int i = 0; i < 64; ++i) s += xr[i] * sWp[i * 32 + o];
        h4[o] = s;
    }
    float h5[32];
    for (int o = 0; o < 32; ++o) {
        float s = sb1[o];
#pragma unroll
        for (int i = 0; i < 32; ++i) s += h4[i] * sW1[i * 32 + o];
        h5[o] = leaky(s);
    }
#pragma unroll
    for (int o = 0; o < 2; ++o) {
        float s = sb2[o];
#pragma unroll
        for (int i = 0; i < 32; ++i) s += h5[i] * sW2[i * 2 + o];
        out[(size_t)row * 2 + o] = s;
    }
}

// ---------------- launch ----------------
extern "C" void kernel_launch(void* const* d_in, const int* in_sizes, int n_in,
                              void* d_out, int out_size, void* d_ws, size_t ws_size,
                              hipStream_t stream) {
    const float* x   = (const float*)d_in[0];
    const int*   ei  = (const int*)d_in[1];
    const float* W1l = (const float*)d_in[5];
    const float* b1  = (const float*)d_in[6];
    const float* W1r = (const float*)d_in[7];
    const float* W2l = (const float*)d_in[8];
    const float* b2  = (const float*)d_in[9];
    const float* W2r = (const float*)d_in[10];
    const float* W3l = (const float*)d_in[11];
    const float* b3  = (const float*)d_in[12];
    const float* W3r = (const float*)d_in[13];
    const float* Wp  = (const float*)d_in[14];
    const float* bp  = (const float*)d_in[15];
    const float* Wf1 = (const float*)d_in[16];
    const float* bf1 = (const float*)d_in[17];
    const float* Wf2 = (const float*)d_in[18];
    const float* bf2 = (const float*)d_in[19];
    float* out = (float*)d_out;
    (void)in_sizes; (void)n_in; (void)out_size; (void)ws_size;

    const int* src = ei;
    const int* dst = ei + N_EDGES;

    char* base = (char*)d_ws;
    size_t off = 0;
    auto alloc = [&](size_t bytes) -> void* {
        void* r = base + off;
        off = (off + bytes + 255) & ~(size_t)255;
        return r;
    };
    const size_t NN = N_NODES;
    int*   cnt    = (int*)alloc(NN * 4);
    int*   offs   = (int*)alloc((NN + 1) * 4);
    int*   cursor = (int*)alloc(NN * 4);
    float* inv    = (float*)alloc(NN * 4);
    int*   bsum   = (int*)alloc(64 * 4);
    int*   ssrc   = (int*)alloc((size_t)N_EDGES * 4);
    u16* w1lh = (u16*)alloc(128 * 512 * 2); u16* w1ll = (u16*)alloc(128 * 512 * 2);
    u16* w1rh = (u16*)alloc(128 * 512 * 2); u16* w1rl = (u16*)alloc(128 * 512 * 2);
    u16* w2ch = (u16*)alloc(512 * 512 * 2); u16* w2cl = (u16*)alloc(512 * 512 * 2);
    u16* w3ch = (u16*)alloc(128 * 256 * 2); u16* w3cl = (u16*)alloc(128 * 256 * 2);

    // Live-range-aliased regions (~205 MB)
    char* regA = (char*)alloc(NN * 256 * 4);       // xh|xl|axh|axl -> z2 -> h3
    char* regB = (char*)alloc(NN * 512 * 2 * 2);   // h1h|h1l -> h2h|h2l
    char* regD = (char*)alloc(NN * 256 * 4);       // y2 -> z3|y3

    u16* xh  = (u16*)regA;
    u16* xl  = xh + NN * 128;
    u16* axh = xl + NN * 128;
    u16* axl = axh + NN * 128;
    u16* h1h = (u16*)regB;
    u16* h1l = h1h + NN * 512;
    float* z2 = (float*)regA;                      // L2 GEMM out; read by agg2 (then dead)
    u16* h2h = (u16*)regB;                         // agg2 epilogue out (h1 dead)
    u16* h2l = h2h + NN * 256;
    float* y2f = (float*)regD;                     // read inside agg2 epilogue (then dead)
    float* z3f = (float*)regD;                     // L3 GEMM out (y2 dead)
    float* y3f = z3f + NN * 64;
    float* h3f = (float*)regA;                     // agg3 epilogue out (z2 dead)

    // CSR + prep
    hipMemsetAsync(cnt, 0, NN * 4, stream);
    k_prep<<<3125 + 6250 + 1664, 256, 0, stream>>>(dst, cnt, x, xh, xl,
        W1l, W1r, W2l, W2r, W3l, W3r,
        w1lh, w1ll, w1rh, w1rl, w2ch, w2cl, w3ch, w3cl);
    const int nb = (N_NODES + 1023) / 1024;   // 49
    k_scan1<<<nb, 1024, 0, stream>>>(cnt, offs, bsum);
    k_scan2<<<1, 64, 0, stream>>>(bsum, nb);
    k_scan3<<<(N_NODES + 255) / 256, 256, 0, stream>>>(cnt, offs, cursor, inv, bsum);
    k_fill<<<(N_EDGES + 255) / 256, 256, 0, stream>>>(src, dst, cursor, ssrc);

    const int aggGrid = (N_NODES + 3) / 4;             // 12500
    const int mT = (N_NODES + 127) / 128;              // 391
    const int grid4 = ((mT + 7) / 8) * 32;             // nct=4
    const int grid1 = ((mT + 7) / 8) * 8;              // nct=1

    // layer 1: aggX = S x (split, 2 chunks); h1 = leaky(aggX@W1l + x@W1r + b1)
    k_agg<64, 128, 8, 1><<<dim3(aggGrid, 2), 256, 0, stream>>>(
        x, offs, ssrc, inv, nullptr, nullptr, nullptr, axh, axl);
    k_gemm_s<<<grid4, 256, 0, stream>>>(N_NODES, 4,
        axh, axl, w1lh, w1ll, 128, xh, xl, w1rh, w1rl, 128,
        b1, 1, 512, nullptr, h1h, h1l, 512, nullptr, 0);

    // layer 2: [z2|y2] = h1 @ [W2l|W2r]; agg2 fused epilogue: h2 = leaky(S z2 + y2 + b2)
    k_gemm_s<<<grid4, 256, 0, stream>>>(N_NODES, 4,
        h1h, h1l, w2ch, w2cl, 512, nullptr, nullptr, nullptr, nullptr, 0,
        nullptr, 0, 256, z2, nullptr, nullptr, 256, y2f, 256);
    k_agg<128, 256, 8, 2><<<dim3(aggGrid, 2), 256, 0, stream>>>(
        z2, offs, ssrc, inv, y2f, b2, nullptr, h2h, h2l);

    // layer 3: [z3|y3] = h2 @ [W3l|W3r]; agg3 fused epilogue: h3 = leaky(S z3 + y3 + b3)
    k_gemm_s<<<grid1, 256, 0, stream>>>(N_NODES, 1,
        h2h, h2l, w3ch, w3cl, 256, nullptr, nullptr, nullptr, nullptr, 0,
        nullptr, 0, 64, z3f, nullptr, nullptr, 64, y3f, 64);
    k_agg<32, 64, 8, 3><<<dim3(aggGrid, 2), 256, 0, stream>>>(
        z3f, offs, ssrc, inv, y3f, b3, h3f, nullptr, nullptr);

    // head: h3 -> pre_fc -> leaky(fc1) -> fc2
    k_head<<<(N_NODES + 255) / 256, 256, 0, stream>>>(h3f,
        Wp, bp, Wf1, bf1, Wf2, bf2, out);
}